// Round 1
// baseline (1082.023 us; speedup 1.0000x reference)
//
#include <hip/hip_runtime.h>
#include <hip/hip_bf16.h>
#include <math.h>

#define B_   2
#define L_   512
#define DM   1024
#define DIP  4352
#define DI   2048
#define NH_  32
#define HD   64
#define DS   64
#define NA   32
#define BL   (B_ * L_)

// proj slice offsets
#define OFF_Z    0
#define OFF_X    2048
#define OFF_BP   4096
#define OFF_CP   4160
#define OFF_DT   4224
#define OFF_DA   4256
#define OFF_TR   4288
#define OFF_ANG  4320

__device__ __forceinline__ float softplusf(float x) {
    // log1p(exp(x)), stable
    return x > 0.f ? x + log1pf(expf(-x)) : log1pf(expf(x));
}
__device__ __forceinline__ float sigmoidf_(float x) {
    return 1.f / (1.f + expf(-x));
}
__device__ __forceinline__ float wave_sum(float v) {
#pragma unroll
    for (int off = 32; off; off >>= 1) v += __shfl_xor(v, off);
    return v;
}

// ---------------- f32 tiled GEMM: C[M,N] = A[M,K] @ B[K,N], row-major -------
// 64x64 tile, BK=16, 256 threads, 4x4 micro-tile per thread.
__global__ __launch_bounds__(256) void gemm64(const float* __restrict__ A,
                                              const float* __restrict__ Bm,
                                              float* __restrict__ C,
                                              int M, int N, int K) {
    __shared__ float As[16][65];
    __shared__ float Bs[16][65];
    const int tx = threadIdx.x & 15;
    const int ty = threadIdx.x >> 4;
    const int brow = blockIdx.y * 64;
    const int bcol = blockIdx.x * 64;
    float acc[4][4] = {};

    for (int k0 = 0; k0 < K; k0 += 16) {
        // A tile: 64 rows x 16 cols
#pragma unroll
        for (int i = threadIdx.x; i < 64 * 16; i += 256) {
            int r = i >> 4, c = i & 15;
            As[c][r] = A[(size_t)(brow + r) * K + k0 + c];
        }
        // B tile: 16 rows x 64 cols
#pragma unroll
        for (int i = threadIdx.x; i < 16 * 64; i += 256) {
            int r = i >> 6, c = i & 63;
            Bs[r][c] = Bm[(size_t)(k0 + r) * N + bcol + c];
        }
        __syncthreads();
#pragma unroll
        for (int kk = 0; kk < 16; ++kk) {
            float a[4], b[4];
#pragma unroll
            for (int i = 0; i < 4; ++i) a[i] = As[kk][ty * 4 + i];
#pragma unroll
            for (int j = 0; j < 4; ++j) b[j] = Bs[kk][tx * 4 + j];
#pragma unroll
            for (int i = 0; i < 4; ++i)
#pragma unroll
                for (int j = 0; j < 4; ++j) acc[i][j] += a[i] * b[j];
        }
        __syncthreads();
    }
#pragma unroll
    for (int i = 0; i < 4; ++i)
#pragma unroll
        for (int j = 0; j < 4; ++j)
            C[(size_t)(brow + ty * 4 + i) * N + bcol + tx * 4 + j] = acc[i][j];
}

// ---------- per-(b,l) small ops: DT, decay, trap, dtmean, LN(Bp), LN(Cp) ----
__global__ __launch_bounds__(64) void small_ops(const float* __restrict__ proj,
                                                const float* __restrict__ dt_bias,
                                                const float* __restrict__ Bn_g,
                                                const float* __restrict__ Bn_b,
                                                const float* __restrict__ Cn_g,
                                                const float* __restrict__ Cn_b,
                                                float* __restrict__ DTa,
                                                float* __restrict__ deca,
                                                float* __restrict__ trpa,
                                                float* __restrict__ dtm,
                                                float* __restrict__ Bln,
                                                float* __restrict__ Cln) {
    const int bl = blockIdx.x;
    const int lane = threadIdx.x;
    const float* p = proj + (size_t)bl * DIP;

    float dt = 0.f;
    if (lane < NH_) {
        dt = softplusf(p[OFF_DT + lane] + dt_bias[lane]);
        DTa[bl * NH_ + lane] = dt;
        float a = -softplusf(p[OFF_DA + lane]);
        a = fminf(a, -1e-4f);
        deca[bl * NH_ + lane] = expf(a * dt);
        trpa[bl * NH_ + lane] = sigmoidf_(p[OFF_TR + lane]);
    }
    float s = wave_sum(dt);
    if (lane == 0) dtm[bl] = s * (1.f / NH_);

    // LayerNorm Bp over 64
    {
        float v = p[OFF_BP + lane];
        float m = wave_sum(v) * (1.f / 64.f);
        float d = v - m;
        float var = wave_sum(d * d) * (1.f / 64.f);
        Bln[bl * DS + lane] = d / sqrtf(var + 1e-5f) * Bn_g[lane] + Bn_b[lane];
    }
    // LayerNorm Cp over 64
    {
        float v = p[OFF_CP + lane];
        float m = wave_sum(v) * (1.f / 64.f);
        float d = v - m;
        float var = wave_sum(d * d) * (1.f / 64.f);
        Cln[bl * DS + lane] = d / sqrtf(var + 1e-5f) * Cn_g[lane] + Cn_b[lane];
    }
}

// ---------- phase cumsum over L + RoPE application (serial over L) ----------
__global__ __launch_bounds__(32) void rope_k(const float* __restrict__ proj,
                                             const float* __restrict__ dtm,
                                             const float* __restrict__ Bln,
                                             const float* __restrict__ Cln,
                                             float* __restrict__ Brot,
                                             float* __restrict__ Crot) {
    const int b = blockIdx.x;   // 0..1
    const int a = threadIdx.x;  // 0..31 (angle pair)
    float phase = 0.f;
    for (int l = 0; l < L_; ++l) {
        const int bl = b * L_ + l;
        phase += proj[(size_t)bl * DIP + OFF_ANG + a] * dtm[bl];
        float c, s;
        __sincosf(phase, &s, &c);
        {
            float ve = Bln[bl * DS + 2 * a], vo = Bln[bl * DS + 2 * a + 1];
            Brot[bl * DS + 2 * a]     = ve * c - vo * s;
            Brot[bl * DS + 2 * a + 1] = ve * s + vo * c;
        }
        {
            float ve = Cln[bl * DS + 2 * a], vo = Cln[bl * DS + 2 * a + 1];
            Crot[bl * DS + 2 * a]     = ve * c - vo * s;
            Crot[bl * DS + 2 * a + 1] = ve * s + vo * c;
        }
    }
}

// ---------- selective scan: one wave per (b,h,p), lane = n ------------------
__global__ __launch_bounds__(256) void scan_k(const float* __restrict__ proj,
                                              const float* __restrict__ Brot,
                                              const float* __restrict__ Crot,
                                              const float* __restrict__ DTa,
                                              const float* __restrict__ deca,
                                              const float* __restrict__ trpa,
                                              const float* __restrict__ D_param,
                                              float* __restrict__ yact) {
    const int wave = (blockIdx.x * blockDim.x + threadIdx.x) >> 6;  // 0..4095
    const int lane = threadIdx.x & 63;                              // n
    const int p_ = wave & 63;          // head dim
    const int h  = (wave >> 6) & 31;   // head
    const int b  = wave >> 11;         // batch

    float hstate = 0.f;
    float bxprev = 0.f;
    const float Dp = D_param[h];

    for (int l = 0; l < L_; ++l) {
        const int bl = b * L_ + l;
        const float* pr = proj + (size_t)bl * DIP;
        float x  = pr[OFF_X + h * HD + p_];
        float z  = pr[OFF_Z + h * HD + p_];
        float d  = deca[bl * NH_ + h];
        float dt = DTa[bl * NH_ + h];
        float te = trpa[bl * NH_ + h];
        float Bn = Brot[bl * DS + lane];
        float Cn = Crot[bl * DS + lane];

        float bx = x * Bn;
        float inp = (te * bx + (1.f - te) * bxprev) * dt;
        bxprev = bx;
        hstate = d * hstate + inp;

        float part = hstate * Cn;
#pragma unroll
        for (int off = 32; off; off >>= 1) part += __shfl_xor(part, off);
        if (lane == 0) {
            float yv = part + Dp * x;
            float sil = z * sigmoidf_(z);
            yact[(size_t)bl * DI + h * HD + p_] = yv * sil;
        }
    }
}

extern "C" void kernel_launch(void* const* d_in, const int* in_sizes, int n_in,
                              void* d_out, int out_size, void* d_ws, size_t ws_size,
                              hipStream_t stream) {
    const float* u       = (const float*)d_in[0];
    const float* W_in    = (const float*)d_in[1];
    const float* W_out   = (const float*)d_in[2];
    const float* dt_bias = (const float*)d_in[3];
    const float* D_param = (const float*)d_in[4];
    const float* Bn_g    = (const float*)d_in[5];
    const float* Bn_b    = (const float*)d_in[6];
    const float* Cn_g    = (const float*)d_in[7];
    const float* Cn_b    = (const float*)d_in[8];
    float* out = (float*)d_out;

    float* ws   = (float*)d_ws;
    float* proj = ws;                    // BL*DIP = 4456448
    float* Bln  = proj + (size_t)BL * DIP;
    float* Cln  = Bln + BL * DS;         // 65536 each
    float* Brot = Cln + BL * DS;
    float* Crot = Brot + BL * DS;
    float* DTa  = Crot + BL * DS;
    float* deca = DTa + BL * NH_;        // 32768 each
    float* trpa = deca + BL * NH_;
    float* dtm  = trpa + BL * NH_;
    float* yact = dtm + BL;              // BL*DI = 2097152

    // 1) in-projection: (BL x DM) @ (DM x DIP)
    gemm64<<<dim3(DIP / 64, BL / 64), dim3(256), 0, stream>>>(u, W_in, proj, BL, DIP, DM);
    // 2) per-(b,l) small ops
    small_ops<<<dim3(BL), dim3(64), 0, stream>>>(proj, dt_bias, Bn_g, Bn_b, Cn_g, Cn_b,
                                                 DTa, deca, trpa, dtm, Bln, Cln);
    // 3) phase cumsum + RoPE
    rope_k<<<dim3(B_), dim3(NA), 0, stream>>>(proj, dtm, Bln, Cln, Brot, Crot);
    // 4) selective scan + gate
    scan_k<<<dim3((B_ * NH_ * HD * 64) / 256), dim3(256), 0, stream>>>(
        proj, Brot, Crot, DTa, deca, trpa, D_param, yact);
    // 5) out-projection: (BL x DI) @ (DI x DM)
    gemm64<<<dim3(DM / 64, BL / 64), dim3(256), 0, stream>>>(yact, W_out, out, BL, DM, DI);
}

// Round 2
// 591.309 us; speedup vs baseline: 1.8299x; 1.8299x over previous
//
#include <hip/hip_runtime.h>
#include <hip/hip_bf16.h>
#include <math.h>

#define B_   2
#define L_   512
#define DM   1024
#define DIP  4352
#define DI   2048
#define NH_  32
#define HD   64
#define DS   64
#define NA   32
#define BL   (B_ * L_)
#define CHK  32
#define NCH  16

// proj slice offsets
#define OFF_Z    0
#define OFF_X    2048
#define OFF_BP   4096
#define OFF_CP   4160
#define OFF_DT   4224
#define OFF_DA   4256
#define OFF_TR   4288
#define OFF_ANG  4320

__device__ __forceinline__ float softplusf(float x) {
    return x > 0.f ? x + log1pf(expf(-x)) : log1pf(expf(x));
}
__device__ __forceinline__ float sigmoidf_(float x) {
    return 1.f / (1.f + expf(-x));
}
__device__ __forceinline__ float wave_sum(float v) {
#pragma unroll
    for (int off = 32; off; off >>= 1) v += __shfl_xor(v, off);
    return v;
}

// ---------------- f32 GEMM 128x128 tile, 8x8 micro (for in-proj) ------------
__global__ __launch_bounds__(256) void gemm128(const float* __restrict__ A,
                                               const float* __restrict__ Bm,
                                               float* __restrict__ C,
                                               int M, int N, int K) {
    __shared__ float As[16][132];
    __shared__ float Bs[16][132];
    const int tid = threadIdx.x;
    const int tx = tid & 15;
    const int ty = tid >> 4;
    const int brow = blockIdx.y * 128;
    const int bcol = blockIdx.x * 128;
    float acc[8][8] = {};

    for (int k0 = 0; k0 < K; k0 += 16) {
#pragma unroll
        for (int i = 0; i < 2; ++i) {
            int idx = tid + i * 256;          // 0..511
            int r = idx >> 2, c4 = idx & 3;   // A: 128 rows x 4 float4
            float4 v = *(const float4*)&A[(size_t)(brow + r) * K + k0 + c4 * 4];
            As[c4 * 4 + 0][r] = v.x;
            As[c4 * 4 + 1][r] = v.y;
            As[c4 * 4 + 2][r] = v.z;
            As[c4 * 4 + 3][r] = v.w;
        }
#pragma unroll
        for (int i = 0; i < 2; ++i) {
            int idx = tid + i * 256;
            int kk = idx >> 5, c4 = idx & 31;  // B: 16 k x 32 float4
            float4 v = *(const float4*)&Bm[(size_t)(k0 + kk) * N + bcol + c4 * 4];
            *(float4*)&Bs[kk][c4 * 4] = v;
        }
        __syncthreads();
#pragma unroll
        for (int kk = 0; kk < 16; ++kk) {
            float a[8], b[8];
            float4 a0 = *(const float4*)&As[kk][ty * 8];
            float4 a1 = *(const float4*)&As[kk][ty * 8 + 4];
            float4 b0 = *(const float4*)&Bs[kk][tx * 8];
            float4 b1 = *(const float4*)&Bs[kk][tx * 8 + 4];
            a[0]=a0.x;a[1]=a0.y;a[2]=a0.z;a[3]=a0.w;a[4]=a1.x;a[5]=a1.y;a[6]=a1.z;a[7]=a1.w;
            b[0]=b0.x;b[1]=b0.y;b[2]=b0.z;b[3]=b0.w;b[4]=b1.x;b[5]=b1.y;b[6]=b1.z;b[7]=b1.w;
#pragma unroll
            for (int i = 0; i < 8; ++i)
#pragma unroll
                for (int j = 0; j < 8; ++j) acc[i][j] = fmaf(a[i], b[j], acc[i][j]);
        }
        __syncthreads();
    }
#pragma unroll
    for (int i = 0; i < 8; ++i) {
        float4 v0 = make_float4(acc[i][0], acc[i][1], acc[i][2], acc[i][3]);
        float4 v1 = make_float4(acc[i][4], acc[i][5], acc[i][6], acc[i][7]);
        float* cp = &C[(size_t)(brow + ty * 8 + i) * N + bcol + tx * 8];
        *(float4*)cp = v0;
        *(float4*)(cp + 4) = v1;
    }
}

// ---------------- f32 GEMM 64x64 tile (for out-proj: only 64 col-tiles) -----
__global__ __launch_bounds__(256) void gemm64(const float* __restrict__ A,
                                              const float* __restrict__ Bm,
                                              float* __restrict__ C,
                                              int M, int N, int K) {
    __shared__ float As[16][65];
    __shared__ float Bs[16][65];
    const int tx = threadIdx.x & 15;
    const int ty = threadIdx.x >> 4;
    const int brow = blockIdx.y * 64;
    const int bcol = blockIdx.x * 64;
    float acc[4][4] = {};

    for (int k0 = 0; k0 < K; k0 += 16) {
#pragma unroll
        for (int i = threadIdx.x; i < 64 * 16; i += 256) {
            int r = i >> 4, c = i & 15;
            As[c][r] = A[(size_t)(brow + r) * K + k0 + c];
        }
#pragma unroll
        for (int i = threadIdx.x; i < 16 * 64; i += 256) {
            int r = i >> 6, c = i & 63;
            Bs[r][c] = Bm[(size_t)(k0 + r) * N + bcol + c];
        }
        __syncthreads();
#pragma unroll
        for (int kk = 0; kk < 16; ++kk) {
            float a[4], b[4];
#pragma unroll
            for (int i = 0; i < 4; ++i) a[i] = As[kk][ty * 4 + i];
#pragma unroll
            for (int j = 0; j < 4; ++j) b[j] = Bs[kk][tx * 4 + j];
#pragma unroll
            for (int i = 0; i < 4; ++i)
#pragma unroll
                for (int j = 0; j < 4; ++j) acc[i][j] += a[i] * b[j];
        }
        __syncthreads();
    }
#pragma unroll
    for (int i = 0; i < 4; ++i)
#pragma unroll
        for (int j = 0; j < 4; ++j)
            C[(size_t)(brow + ty * 4 + i) * N + bcol + tx * 4 + j] = acc[i][j];
}

// ---------- per-(b,l) small ops: DT, decay, trap, dtmean, LN(Bp), LN(Cp) ----
__global__ __launch_bounds__(64) void small_ops(const float* __restrict__ proj,
                                                const float* __restrict__ dt_bias,
                                                const float* __restrict__ Bn_g,
                                                const float* __restrict__ Bn_b,
                                                const float* __restrict__ Cn_g,
                                                const float* __restrict__ Cn_b,
                                                float* __restrict__ DTa,
                                                float* __restrict__ deca,
                                                float* __restrict__ trpa,
                                                float* __restrict__ dtm,
                                                float* __restrict__ Bln,
                                                float* __restrict__ Cln) {
    const int bl = blockIdx.x;
    const int lane = threadIdx.x;
    const float* p = proj + (size_t)bl * DIP;

    float dt = 0.f;
    if (lane < NH_) {
        dt = softplusf(p[OFF_DT + lane] + dt_bias[lane]);
        DTa[bl * NH_ + lane] = dt;
        float a = -softplusf(p[OFF_DA + lane]);
        a = fminf(a, -1e-4f);
        deca[bl * NH_ + lane] = expf(a * dt);
        trpa[bl * NH_ + lane] = sigmoidf_(p[OFF_TR + lane]);
    }
    float s = wave_sum(dt);
    if (lane == 0) dtm[bl] = s * (1.f / NH_);

    {
        float v = p[OFF_BP + lane];
        float m = wave_sum(v) * (1.f / 64.f);
        float d = v - m;
        float var = wave_sum(d * d) * (1.f / 64.f);
        Bln[bl * DS + lane] = d / sqrtf(var + 1e-5f) * Bn_g[lane] + Bn_b[lane];
    }
    {
        float v = p[OFF_CP + lane];
        float m = wave_sum(v) * (1.f / 64.f);
        float d = v - m;
        float var = wave_sum(d * d) * (1.f / 64.f);
        Cln[bl * DS + lane] = d / sqrtf(var + 1e-5f) * Cn_g[lane] + Cn_b[lane];
    }
}

// ---------- blocked parallel cumsum of phase: one wave per (b, angle) -------
__global__ __launch_bounds__(64) void phase_scan(const float* __restrict__ proj,
                                                 const float* __restrict__ dtm,
                                                 float* __restrict__ phase) {
    const int b = blockIdx.x >> 5;
    const int a = blockIdx.x & 31;
    const int lane = threadIdx.x;
    float s[8];
    float run = 0.f;
#pragma unroll
    for (int j = 0; j < 8; ++j) {
        const int bl = b * L_ + lane * 8 + j;
        run += proj[(size_t)bl * DIP + OFF_ANG + a] * dtm[bl];
        s[j] = run;
    }
    float inc = run;
#pragma unroll
    for (int off = 1; off < 64; off <<= 1) {
        float v = __shfl_up(inc, off);
        if (lane >= off) inc += v;
    }
    const float excl = inc - run;
#pragma unroll
    for (int j = 0; j < 8; ++j)
        phase[(b * L_ + lane * 8 + j) * NA + a] = excl + s[j];
}

// ---------- parallel RoPE application ---------------------------------------
__global__ __launch_bounds__(64) void rope_apply(const float* __restrict__ phase,
                                                 const float* __restrict__ Bln,
                                                 const float* __restrict__ Cln,
                                                 float* __restrict__ Brot,
                                                 float* __restrict__ Crot) {
    const int bl = blockIdx.x;
    const int lane = threadIdx.x;
    const int pr = lane >> 1;
    const float ph = phase[bl * NA + pr];
    float sn, cs;
    __sincosf(ph, &sn, &cs);
    const bool odd = lane & 1;
    {
        float ve = Bln[bl * DS + pr * 2], vo = Bln[bl * DS + pr * 2 + 1];
        Brot[bl * DS + lane] = odd ? (ve * sn + vo * cs) : (ve * cs - vo * sn);
    }
    {
        float ve = Cln[bl * DS + pr * 2], vo = Cln[bl * DS + pr * 2 + 1];
        Crot[bl * DS + lane] = odd ? (ve * sn + vo * cs) : (ve * cs - vo * sn);
    }
}

// ---------- scan phase A: local chunk scan, lane = p, state in VGPRs --------
__global__ __launch_bounds__(64) void scanA(const float* __restrict__ proj,
                                            const float* __restrict__ Brot,
                                            const float* __restrict__ Crot,
                                            const float* __restrict__ DTa,
                                            const float* __restrict__ deca,
                                            const float* __restrict__ trpa,
                                            float* __restrict__ yact,
                                            float* __restrict__ hend) {
    __shared__ float Bbuf[2][64];
    __shared__ float Cbuf[2][64];
    const int blk = blockIdx.x;
    const int c  = blk & 15;
    const int bh = blk >> 4;
    const int h  = bh & 31;
    const int b  = bh >> 5;
    const int lane = threadIdx.x;   // = p
    const int l0 = c * CHK;
    const int bl0 = b * L_ + l0;

    float4 h4[16];
#pragma unroll
    for (int i = 0; i < 16; ++i) h4[i] = make_float4(0.f, 0.f, 0.f, 0.f);

    float xprev = 0.f, bprev0 = 0.f;
    if (c > 0) {
        xprev  = proj[(size_t)(bl0 - 1) * DIP + OFF_X + h * HD + lane];
        bprev0 = Brot[(bl0 - 1) * DS + lane];
    }
    Bbuf[1][lane] = bprev0;   // slot for "previous of i=0"

    float Bnext = Brot[bl0 * DS + lane];
    float Cnext = Crot[bl0 * DS + lane];

    for (int i = 0; i < CHK; ++i) {
        const int bl = bl0 + i;
        const int cur = i & 1;
        Bbuf[cur][lane] = Bnext;
        Cbuf[cur][lane] = Cnext;
        __syncthreads();
        if (i + 1 < CHK) {
            Bnext = Brot[(bl + 1) * DS + lane];
            Cnext = Crot[(bl + 1) * DS + lane];
        }
        const float d  = deca[bl * NH_ + h];
        const float dt = DTa[bl * NH_ + h];
        const float te = trpa[bl * NH_ + h];
        const float x  = proj[(size_t)bl * DIP + OFF_X + h * HD + lane];
        const float ac = dt * te * x;
        const float bc = dt * (1.f - te) * xprev;
        xprev = x;
        const float4* Bc = (const float4*)Bbuf[cur];
        const float4* Bp = (const float4*)Bbuf[cur ^ 1];
        const float4* Cc = (const float4*)Cbuf[cur];
        float4 yv = make_float4(0.f, 0.f, 0.f, 0.f);
#pragma unroll
        for (int n4 = 0; n4 < 16; ++n4) {
            float4 bb = Bc[n4], bp = Bp[n4], cc = Cc[n4];
            h4[n4].x = fmaf(d, h4[n4].x, fmaf(ac, bb.x, bc * bp.x)); yv.x = fmaf(h4[n4].x, cc.x, yv.x);
            h4[n4].y = fmaf(d, h4[n4].y, fmaf(ac, bb.y, bc * bp.y)); yv.y = fmaf(h4[n4].y, cc.y, yv.y);
            h4[n4].z = fmaf(d, h4[n4].z, fmaf(ac, bb.z, bc * bp.z)); yv.z = fmaf(h4[n4].z, cc.z, yv.z);
            h4[n4].w = fmaf(d, h4[n4].w, fmaf(ac, bb.w, bc * bp.w)); yv.w = fmaf(h4[n4].w, cc.w, yv.w);
        }
        yact[(size_t)bl * DI + h * HD + lane] = (yv.x + yv.y) + (yv.z + yv.w);
        __syncthreads();
    }
    const size_t hbase = (size_t)(bh * NCH + c) * 64 * 64;
#pragma unroll
    for (int n4 = 0; n4 < 16; ++n4) {
        hend[hbase + (size_t)(n4 * 4 + 0) * 64 + lane] = h4[n4].x;
        hend[hbase + (size_t)(n4 * 4 + 1) * 64 + lane] = h4[n4].y;
        hend[hbase + (size_t)(n4 * 4 + 2) * 64 + lane] = h4[n4].z;
        hend[hbase + (size_t)(n4 * 4 + 3) * 64 + lane] = h4[n4].w;
    }
}

// ---------- scan phase B: combine chunk states (h0[c] -> stored at slot c-1)-
__global__ __launch_bounds__(256) void scanB(const float* __restrict__ deca,
                                             float* __restrict__ hend) {
    __shared__ float Pl[NCH];
    const int bh = blockIdx.x;
    const int h = bh & 31, b = bh >> 5;
    const int tid = threadIdx.x;
    if (tid < NCH) {
        float p = 1.f;
        for (int j = 0; j < CHK; ++j)
            p *= deca[(b * L_ + tid * CHK + j) * NH_ + h];
        Pl[tid] = p;
    }
    __syncthreads();
    float run[16];
#pragma unroll
    for (int k = 0; k < 16; ++k) run[k] = 0.f;
    for (int cc = 1; cc < NCH; ++cc) {
        const float Pc = Pl[cc - 1];
        const size_t base = (size_t)(bh * NCH + (cc - 1)) * 4096;
#pragma unroll
        for (int k = 0; k < 16; ++k) {
            const size_t e = base + tid + k * 256;
            float he = hend[e];
            run[k] = fmaf(Pc, run[k], he);
            hend[e] = run[k];   // now holds h0 for chunk cc
        }
    }
}

// ---------- scan phase C: h0 correction + D-skip + SiLU gate (in-place) -----
__global__ __launch_bounds__(64) void scanC(const float* __restrict__ proj,
                                            const float* __restrict__ Crot,
                                            const float* __restrict__ deca,
                                            const float* __restrict__ hend,
                                            const float* __restrict__ D_param,
                                            float* __restrict__ yact) {
    __shared__ float Cbuf[2][64];
    const int blk = blockIdx.x;
    const int c = blk & 15;
    const int bh = blk >> 4;
    const int h = bh & 31, b = bh >> 5;
    const int lane = threadIdx.x;
    const int l0 = c * CHK, bl0 = b * L_ + l0;

    float4 h0[16];
    if (c > 0) {
        const size_t base = (size_t)(bh * NCH + (c - 1)) * 4096;
#pragma unroll
        for (int n4 = 0; n4 < 16; ++n4) {
            h0[n4].x = hend[base + (size_t)(n4 * 4 + 0) * 64 + lane];
            h0[n4].y = hend[base + (size_t)(n4 * 4 + 1) * 64 + lane];
            h0[n4].z = hend[base + (size_t)(n4 * 4 + 2) * 64 + lane];
            h0[n4].w = hend[base + (size_t)(n4 * 4 + 3) * 64 + lane];
        }
    } else {
#pragma unroll
        for (int n4 = 0; n4 < 16; ++n4) h0[n4] = make_float4(0.f, 0.f, 0.f, 0.f);
    }
    const float Dp = D_param[h];
    float w = 1.f;
    float Cnext = Crot[bl0 * DS + lane];
    for (int i = 0; i < CHK; ++i) {
        const int bl = bl0 + i;
        const int cur = i & 1;
        Cbuf[cur][lane] = Cnext;
        __syncthreads();
        if (i + 1 < CHK) Cnext = Crot[(bl + 1) * DS + lane];
        w *= deca[bl * NH_ + h];
        const float4* Cc = (const float4*)Cbuf[cur];
        float4 dv = make_float4(0.f, 0.f, 0.f, 0.f);
#pragma unroll
        for (int n4 = 0; n4 < 16; ++n4) {
            float4 cc = Cc[n4];
            dv.x = fmaf(cc.x, h0[n4].x, dv.x);
            dv.y = fmaf(cc.y, h0[n4].y, dv.y);
            dv.z = fmaf(cc.z, h0[n4].z, dv.z);
            dv.w = fmaf(cc.w, h0[n4].w, dv.w);
        }
        const float dot = (dv.x + dv.y) + (dv.z + dv.w);
        const float x = proj[(size_t)bl * DIP + OFF_X + h * HD + lane];
        const float z = proj[(size_t)bl * DIP + OFF_Z + h * HD + lane];
        const size_t yi = (size_t)bl * DI + h * HD + lane;
        const float yv = yact[yi] + w * dot + Dp * x;
        yact[yi] = yv * z * sigmoidf_(z);
        __syncthreads();
    }
}

extern "C" void kernel_launch(void* const* d_in, const int* in_sizes, int n_in,
                              void* d_out, int out_size, void* d_ws, size_t ws_size,
                              hipStream_t stream) {
    const float* u       = (const float*)d_in[0];
    const float* W_in    = (const float*)d_in[1];
    const float* W_out   = (const float*)d_in[2];
    const float* dt_bias = (const float*)d_in[3];
    const float* D_param = (const float*)d_in[4];
    const float* Bn_g    = (const float*)d_in[5];
    const float* Bn_b    = (const float*)d_in[6];
    const float* Cn_g    = (const float*)d_in[7];
    const float* Cn_b    = (const float*)d_in[8];
    float* out = (float*)d_out;

    float* ws    = (float*)d_ws;
    float* proj  = ws;                         // 4,456,448
    float* Bln   = proj + (size_t)BL * DIP;
    float* Cln   = Bln + BL * DS;
    float* Brot  = Cln + BL * DS;
    float* Crot  = Brot + BL * DS;
    float* DTa   = Crot + BL * DS;
    float* deca  = DTa + BL * NH_;
    float* trpa  = deca + BL * NH_;
    float* dtm   = trpa + BL * NH_;
    float* phase = dtm + BL;                   // BL*NA
    float* yact  = phase + BL * NA;            // BL*DI
    float* hend  = yact + (size_t)BL * DI;     // 64*16*4096

    // 1) in-projection
    gemm128<<<dim3(DIP / 128, BL / 128), dim3(256), 0, stream>>>(u, W_in, proj, BL, DIP, DM);
    // 2) small per-(b,l) ops
    small_ops<<<dim3(BL), dim3(64), 0, stream>>>(proj, dt_bias, Bn_g, Bn_b, Cn_g, Cn_b,
                                                 DTa, deca, trpa, dtm, Bln, Cln);
    // 3) phase cumsum (blocked parallel) + RoPE
    phase_scan<<<dim3(B_ * NA), dim3(64), 0, stream>>>(proj, dtm, phase);
    rope_apply<<<dim3(BL), dim3(64), 0, stream>>>(phase, Bln, Cln, Brot, Crot);
    // 4) chunked scan
    scanA<<<dim3(B_ * NH_ * NCH), dim3(64), 0, stream>>>(proj, Brot, Crot, DTa, deca, trpa,
                                                         yact, hend);
    scanB<<<dim3(B_ * NH_), dim3(256), 0, stream>>>(deca, hend);
    scanC<<<dim3(B_ * NH_ * NCH), dim3(64), 0, stream>>>(proj, Crot, deca, hend, D_param, yact);
    // 5) out-projection
    gemm64<<<dim3(DM / 64, BL / 64), dim3(256), 0, stream>>>(yact, W_out, out, BL, DM, DI);
}

// Round 3
// 200.374 us; speedup vs baseline: 5.4000x; 2.9510x over previous
//
#include <hip/hip_runtime.h>
#include <hip/hip_bf16.h>
#include <math.h>

#define B_   2
#define L_   512
#define DM   1024
#define DIP  4352
#define DI   2048
#define NH_  32
#define HD   64
#define DS   64
#define NA   32
#define BL   (B_ * L_)
#define CHK  32
#define NCH  16

// proj slice offsets
#define OFF_Z    0
#define OFF_X    2048
#define OFF_BP   4096
#define OFF_CP   4160
#define OFF_DT   4224
#define OFF_DA   4256
#define OFF_TR   4288
#define OFF_ANG  4320

typedef short bf16x8s __attribute__((ext_vector_type(8)));
typedef float f32x4 __attribute__((ext_vector_type(4)));

__device__ __forceinline__ float softplusf(float x) {
    return x > 0.f ? x + log1pf(expf(-x)) : log1pf(expf(x));
}
__device__ __forceinline__ float sigmoidf_(float x) {
    return 1.f / (1.f + expf(-x));
}
__device__ __forceinline__ float wave_sum(float v) {
#pragma unroll
    for (int off = 32; off; off >>= 1) v += __shfl_xor(v, off);
    return v;
}
__device__ __forceinline__ ushort f2bf(float f) {
    uint u = __float_as_uint(f);
    return (ushort)((u + 0x7fffu + ((u >> 16) & 1u)) >> 16);
}

// ---------------- cast f32 -> bf16 (row-major copy) -------------------------
__global__ __launch_bounds__(256) void cast_bf16(const float* __restrict__ in,
                                                 ushort* __restrict__ outp, int n4) {
    int i = blockIdx.x * 256 + threadIdx.x;
    if (i >= n4) return;
    float4 v = ((const float4*)in)[i];
    uint u0 = (uint)f2bf(v.x) | ((uint)f2bf(v.y) << 16);
    uint u1 = (uint)f2bf(v.z) | ((uint)f2bf(v.w) << 16);
    *(uint2*)&outp[(size_t)i * 4] = make_uint2(u0, u1);
}

// ---------------- transpose + cast: in f32 [R][C] -> out bf16 [C][R] --------
__global__ __launch_bounds__(256) void transpose_cast(const float* __restrict__ in,
                                                      ushort* __restrict__ outp,
                                                      int R, int C) {
    __shared__ ushort t[32][33];
    const int tx = threadIdx.x, ty = threadIdx.y;
    const int c0 = blockIdx.x * 32, r0 = blockIdx.y * 32;
#pragma unroll
    for (int j = 0; j < 4; ++j) {
        int r = r0 + ty + j * 8;
        t[ty + j * 8][tx] = f2bf(in[(size_t)r * C + c0 + tx]);
    }
    __syncthreads();
#pragma unroll
    for (int j = 0; j < 4; ++j) {
        int c = c0 + ty + j * 8;
        outp[(size_t)c * R + r0 + tx] = t[tx][ty + j * 8];
    }
}

// ---------------- bf16 MFMA GEMM: C[M,N](f32) = A[M,K] @ BT[N,K] ------------
// 128x128 tile, BK=32, 4 waves (2x2), 16x16x32 MFMA, reg-prefetch dbuf,
// 4-slot XOR LDS swizzle. Optional split-K via blockIdx.z.
__global__ __launch_bounds__(256) void gemm_bf16(const ushort* __restrict__ A,
                                                 const ushort* __restrict__ BT,
                                                 float* __restrict__ C,
                                                 int K, int ldc, int kslice,
                                                 size_t partStride) {
    __shared__ ushort sA[128 * 32];
    __shared__ ushort sB[128 * 32];
    const int tid = threadIdx.x;
    const int l = tid & 63;
    const int w = tid >> 6;
    const int wr = w >> 1, wc = w & 1;
    const int brow = blockIdx.y * 128;
    const int bcol = blockIdx.x * 128;
    const int kstart = blockIdx.z * kslice;
    float* Cp = C + (size_t)blockIdx.z * partStride;

    const int srow = tid >> 2;          // 0..63
    const int gs = tid & 3;             // global 16B slot within 64B row
    // swizzled LDS write slots (involution: slot ^ (row&3))
    const int ws0 = gs ^ (srow & 3);
    const int ws1 = gs ^ ((64 + srow) & 3);

    int4 ra0, ra1, rb0, rb1;
    const ushort* Arow0 = A + (size_t)(brow + srow) * K + gs * 8;
    const ushort* Arow1 = A + (size_t)(brow + 64 + srow) * K + gs * 8;
    const ushort* Brow0 = BT + (size_t)(bcol + srow) * K + gs * 8;
    const ushort* Brow1 = BT + (size_t)(bcol + 64 + srow) * K + gs * 8;

    ra0 = *(const int4*)(Arow0 + kstart);
    ra1 = *(const int4*)(Arow1 + kstart);
    rb0 = *(const int4*)(Brow0 + kstart);
    rb1 = *(const int4*)(Brow1 + kstart);

    f32x4 acc[4][4] = {};

    const int kend = kstart + kslice;
    for (int k0 = kstart; k0 < kend; k0 += 32) {
        __syncthreads();
        *(int4*)&sA[(size_t)srow * 32 + ws0 * 8] = ra0;
        *(int4*)&sA[(size_t)(64 + srow) * 32 + ws1 * 8] = ra1;
        *(int4*)&sB[(size_t)srow * 32 + ws0 * 8] = rb0;
        *(int4*)&sB[(size_t)(64 + srow) * 32 + ws1 * 8] = rb1;
        __syncthreads();
        if (k0 + 32 < kend) {
            ra0 = *(const int4*)(Arow0 + k0 + 32);
            ra1 = *(const int4*)(Arow1 + k0 + 32);
            rb0 = *(const int4*)(Brow0 + k0 + 32);
            rb1 = *(const int4*)(Brow1 + k0 + 32);
        }
        bf16x8s af[4], bfr[4];
#pragma unroll
        for (int m = 0; m < 4; ++m) {
            int row = wr * 64 + m * 16 + (l & 15);
            int slot = (l >> 4) ^ (row & 3);
            af[m] = *(const bf16x8s*)&sA[(size_t)row * 32 + slot * 8];
        }
#pragma unroll
        for (int n = 0; n < 4; ++n) {
            int row = wc * 64 + n * 16 + (l & 15);
            int slot = (l >> 4) ^ (row & 3);
            bfr[n] = *(const bf16x8s*)&sB[(size_t)row * 32 + slot * 8];
        }
#pragma unroll
        for (int m = 0; m < 4; ++m)
#pragma unroll
            for (int n = 0; n < 4; ++n)
                acc[m][n] = __builtin_amdgcn_mfma_f32_16x16x32_bf16(af[m], bfr[n], acc[m][n], 0, 0, 0);
    }
#pragma unroll
    for (int m = 0; m < 4; ++m) {
        const int row0 = brow + wr * 64 + m * 16 + (l >> 4) * 4;
#pragma unroll
        for (int n = 0; n < 4; ++n) {
            const int col = bcol + wc * 64 + n * 16 + (l & 15);
#pragma unroll
            for (int r = 0; r < 4; ++r)
                Cp[(size_t)(row0 + r) * ldc + col] = acc[m][n][r];
        }
    }
}

// ---------------- reduce 4 split-K partials --------------------------------
__global__ __launch_bounds__(256) void reduce4(const float* __restrict__ p,
                                               float* __restrict__ outp) {
    const int i = blockIdx.x * 256 + threadIdx.x;   // float4 index, 262144 total
    float4 a = ((const float4*)p)[i];
    float4 b = ((const float4*)(p + 1048576))[i];
    float4 c = ((const float4*)(p + 2097152))[i];
    float4 d = ((const float4*)(p + 3145728))[i];
    float4 s;
    s.x = (a.x + b.x) + (c.x + d.x);
    s.y = (a.y + b.y) + (c.y + d.y);
    s.z = (a.z + b.z) + (c.z + d.z);
    s.w = (a.w + b.w) + (c.w + d.w);
    ((float4*)outp)[i] = s;
}

// ---------------- exact f32 for the 128 scalar columns (DT/DA/TR/ANG) ------
__global__ __launch_bounds__(256) void skinny_f32(const float* __restrict__ u,
                                                  const float* __restrict__ W_in,
                                                  float* __restrict__ proj) {
    __shared__ float urow[1024];
    __shared__ float part[256];
    const int bl = blockIdx.x;
    for (int i = threadIdx.x; i < 256; i += 256)
        *(float4*)&urow[i * 4] = *(const float4*)&u[(size_t)bl * DM + i * 4];
    __syncthreads();
    const int col = threadIdx.x & 127;
    const int half = threadIdx.x >> 7;
    float s = 0.f;
    const float* wp = W_in + (size_t)(half * 512) * DIP + OFF_DT + col;
    const float* ur = urow + half * 512;
#pragma unroll 4
    for (int k = 0; k < 512; ++k)
        s = fmaf(ur[k], wp[(size_t)k * DIP], s);
    part[threadIdx.x] = s;
    __syncthreads();
    if (threadIdx.x < 128)
        proj[(size_t)bl * DIP + OFF_DT + threadIdx.x] = part[threadIdx.x] + part[threadIdx.x + 128];
}

// ---------- per-(b,l) small ops: DT, decay, trap, dtmean, LN(Bp), LN(Cp) ----
__global__ __launch_bounds__(64) void small_ops(const float* __restrict__ proj,
                                                const float* __restrict__ dt_bias,
                                                const float* __restrict__ Bn_g,
                                                const float* __restrict__ Bn_b,
                                                const float* __restrict__ Cn_g,
                                                const float* __restrict__ Cn_b,
                                                float* __restrict__ DTa,
                                                float* __restrict__ deca,
                                                float* __restrict__ trpa,
                                                float* __restrict__ dtm,
                                                float* __restrict__ Bln,
                                                float* __restrict__ Cln) {
    const int bl = blockIdx.x;
    const int lane = threadIdx.x;
    const float* p = proj + (size_t)bl * DIP;

    float dt = 0.f;
    if (lane < NH_) {
        dt = softplusf(p[OFF_DT + lane] + dt_bias[lane]);
        DTa[bl * NH_ + lane] = dt;
        float a = -softplusf(p[OFF_DA + lane]);
        a = fminf(a, -1e-4f);
        deca[bl * NH_ + lane] = expf(a * dt);
        trpa[bl * NH_ + lane] = sigmoidf_(p[OFF_TR + lane]);
    }
    float s = wave_sum(dt);
    if (lane == 0) dtm[bl] = s * (1.f / NH_);

    {
        float v = p[OFF_BP + lane];
        float m = wave_sum(v) * (1.f / 64.f);
        float d = v - m;
        float var = wave_sum(d * d) * (1.f / 64.f);
        Bln[bl * DS + lane] = d / sqrtf(var + 1e-5f) * Bn_g[lane] + Bn_b[lane];
    }
    {
        float v = p[OFF_CP + lane];
        float m = wave_sum(v) * (1.f / 64.f);
        float d = v - m;
        float var = wave_sum(d * d) * (1.f / 64.f);
        Cln[bl * DS + lane] = d / sqrtf(var + 1e-5f) * Cn_g[lane] + Cn_b[lane];
    }
}

// ---------- blocked parallel cumsum of phase: one wave per (b, angle) -------
__global__ __launch_bounds__(64) void phase_scan(const float* __restrict__ proj,
                                                 const float* __restrict__ dtm,
                                                 float* __restrict__ phase) {
    const int b = blockIdx.x >> 5;
    const int a = blockIdx.x & 31;
    const int lane = threadIdx.x;
    float s[8];
    float run = 0.f;
#pragma unroll
    for (int j = 0; j < 8; ++j) {
        const int bl = b * L_ + lane * 8 + j;
        run += proj[(size_t)bl * DIP + OFF_ANG + a] * dtm[bl];
        s[j] = run;
    }
    float inc = run;
#pragma unroll
    for (int off = 1; off < 64; off <<= 1) {
        float v = __shfl_up(inc, off);
        if (lane >= off) inc += v;
    }
    const float excl = inc - run;
#pragma unroll
    for (int j = 0; j < 8; ++j)
        phase[(b * L_ + lane * 8 + j) * NA + a] = excl + s[j];
}

// ---------- parallel RoPE application ---------------------------------------
__global__ __launch_bounds__(64) void rope_apply(const float* __restrict__ phase,
                                                 const float* __restrict__ Bln,
                                                 const float* __restrict__ Cln,
                                                 float* __restrict__ Brot,
                                                 float* __restrict__ Crot) {
    const int bl = blockIdx.x;
    const int lane = threadIdx.x;
    const int pr = lane >> 1;
    const float ph = phase[bl * NA + pr];
    float sn, cs;
    __sincosf(ph, &sn, &cs);
    const bool odd = lane & 1;
    {
        float ve = Bln[bl * DS + pr * 2], vo = Bln[bl * DS + pr * 2 + 1];
        Brot[bl * DS + lane] = odd ? (ve * sn + vo * cs) : (ve * cs - vo * sn);
    }
    {
        float ve = Cln[bl * DS + pr * 2], vo = Cln[bl * DS + pr * 2 + 1];
        Crot[bl * DS + lane] = odd ? (ve * sn + vo * cs) : (ve * cs - vo * sn);
    }
}

// ---------- scan phase A: local chunk scan, lane = p, state in VGPRs --------
__global__ __launch_bounds__(64) void scanA(const float* __restrict__ proj,
                                            const float* __restrict__ Brot,
                                            const float* __restrict__ Crot,
                                            const float* __restrict__ DTa,
                                            const float* __restrict__ deca,
                                            const float* __restrict__ trpa,
                                            float* __restrict__ yact,
                                            float* __restrict__ hend) {
    __shared__ float Bbuf[2][64];
    __shared__ float Cbuf[2][64];
    const int blk = blockIdx.x;
    const int c  = blk & 15;
    const int bh = blk >> 4;
    const int h  = bh & 31;
    const int b  = bh >> 5;
    const int lane = threadIdx.x;   // = p
    const int l0 = c * CHK;
    const int bl0 = b * L_ + l0;

    float4 h4[16];
#pragma unroll
    for (int i = 0; i < 16; ++i) h4[i] = make_float4(0.f, 0.f, 0.f, 0.f);

    float xprev = 0.f, bprev0 = 0.f;
    if (c > 0) {
        xprev  = proj[(size_t)(bl0 - 1) * DIP + OFF_X + h * HD + lane];
        bprev0 = Brot[(bl0 - 1) * DS + lane];
    }
    Bbuf[1][lane] = bprev0;

    float Bnext = Brot[bl0 * DS + lane];
    float Cnext = Crot[bl0 * DS + lane];

    for (int i = 0; i < CHK; ++i) {
        const int bl = bl0 + i;
        const int cur = i & 1;
        Bbuf[cur][lane] = Bnext;
        Cbuf[cur][lane] = Cnext;
        __syncthreads();
        if (i + 1 < CHK) {
            Bnext = Brot[(bl + 1) * DS + lane];
            Cnext = Crot[(bl + 1) * DS + lane];
        }
        const float d  = deca[bl * NH_ + h];
        const float dt = DTa[bl * NH_ + h];
        const float te = trpa[bl * NH_ + h];
        const float x  = proj[(size_t)bl * DIP + OFF_X + h * HD + lane];
        const float ac = dt * te * x;
        const float bc = dt * (1.f - te) * xprev;
        xprev = x;
        const float4* Bc = (const float4*)Bbuf[cur];
        const float4* Bp = (const float4*)Bbuf[cur ^ 1];
        const float4* Cc = (const float4*)Cbuf[cur];
        float4 yv = make_float4(0.f, 0.f, 0.f, 0.f);
#pragma unroll
        for (int n4 = 0; n4 < 16; ++n4) {
            float4 bb = Bc[n4], bp = Bp[n4], cc = Cc[n4];
            h4[n4].x = fmaf(d, h4[n4].x, fmaf(ac, bb.x, bc * bp.x)); yv.x = fmaf(h4[n4].x, cc.x, yv.x);
            h4[n4].y = fmaf(d, h4[n4].y, fmaf(ac, bb.y, bc * bp.y)); yv.y = fmaf(h4[n4].y, cc.y, yv.y);
            h4[n4].z = fmaf(d, h4[n4].z, fmaf(ac, bb.z, bc * bp.z)); yv.z = fmaf(h4[n4].z, cc.z, yv.z);
            h4[n4].w = fmaf(d, h4[n4].w, fmaf(ac, bb.w, bc * bp.w)); yv.w = fmaf(h4[n4].w, cc.w, yv.w);
        }
        yact[(size_t)bl * DI + h * HD + lane] = (yv.x + yv.y) + (yv.z + yv.w);
        __syncthreads();
    }
    const size_t hbase = (size_t)(bh * NCH + c) * 64 * 64;
#pragma unroll
    for (int n4 = 0; n4 < 16; ++n4) {
        hend[hbase + (size_t)(n4 * 4 + 0) * 64 + lane] = h4[n4].x;
        hend[hbase + (size_t)(n4 * 4 + 1) * 64 + lane] = h4[n4].y;
        hend[hbase + (size_t)(n4 * 4 + 2) * 64 + lane] = h4[n4].z;
        hend[hbase + (size_t)(n4 * 4 + 3) * 64 + lane] = h4[n4].w;
    }
}

// ---------- scan phase B: combine chunk states ------------------------------
__global__ __launch_bounds__(256) void scanB(const float* __restrict__ deca,
                                             float* __restrict__ hend) {
    __shared__ float Pl[NCH];
    const int bh = blockIdx.x;
    const int h = bh & 31, b = bh >> 5;
    const int tid = threadIdx.x;
    if (tid < NCH) {
        float p = 1.f;
        for (int j = 0; j < CHK; ++j)
            p *= deca[(b * L_ + tid * CHK + j) * NH_ + h];
        Pl[tid] = p;
    }
    __syncthreads();
    float run[16];
#pragma unroll
    for (int k = 0; k < 16; ++k) run[k] = 0.f;
    for (int cc = 1; cc < NCH; ++cc) {
        const float Pc = Pl[cc - 1];
        const size_t base = (size_t)(bh * NCH + (cc - 1)) * 4096;
#pragma unroll
        for (int k = 0; k < 16; ++k) {
            const size_t e = base + tid + k * 256;
            float he = hend[e];
            run[k] = fmaf(Pc, run[k], he);
            hend[e] = run[k];
        }
    }
}

// ---------- scan phase C: h0 correction + D-skip + SiLU gate -> bf16 --------
__global__ __launch_bounds__(64) void scanC(const float* __restrict__ proj,
                                            const float* __restrict__ Crot,
                                            const float* __restrict__ deca,
                                            const float* __restrict__ hend,
                                            const float* __restrict__ D_param,
                                            const float* __restrict__ yact,
                                            ushort* __restrict__ ybf) {
    __shared__ float Cbuf[2][64];
    const int blk = blockIdx.x;
    const int c = blk & 15;
    const int bh = blk >> 4;
    const int h = bh & 31, b = bh >> 5;
    const int lane = threadIdx.x;
    const int l0 = c * CHK, bl0 = b * L_ + l0;

    float4 h0[16];
    if (c > 0) {
        const size_t base = (size_t)(bh * NCH + (c - 1)) * 4096;
#pragma unroll
        for (int n4 = 0; n4 < 16; ++n4) {
            h0[n4].x = hend[base + (size_t)(n4 * 4 + 0) * 64 + lane];
            h0[n4].y = hend[base + (size_t)(n4 * 4 + 1) * 64 + lane];
            h0[n4].z = hend[base + (size_t)(n4 * 4 + 2) * 64 + lane];
            h0[n4].w = hend[base + (size_t)(n4 * 4 + 3) * 64 + lane];
        }
    } else {
#pragma unroll
        for (int n4 = 0; n4 < 16; ++n4) h0[n4] = make_float4(0.f, 0.f, 0.f, 0.f);
    }
    const float Dp = D_param[h];
    float w = 1.f;
    float Cnext = Crot[bl0 * DS + lane];
    for (int i = 0; i < CHK; ++i) {
        const int bl = bl0 + i;
        const int cur = i & 1;
        Cbuf[cur][lane] = Cnext;
        __syncthreads();
        if (i + 1 < CHK) Cnext = Crot[(bl + 1) * DS + lane];
        w *= deca[bl * NH_ + h];
        const float4* Cc = (const float4*)Cbuf[cur];
        float4 dv = make_float4(0.f, 0.f, 0.f, 0.f);
#pragma unroll
        for (int n4 = 0; n4 < 16; ++n4) {
            float4 cc = Cc[n4];
            dv.x = fmaf(cc.x, h0[n4].x, dv.x);
            dv.y = fmaf(cc.y, h0[n4].y, dv.y);
            dv.z = fmaf(cc.z, h0[n4].z, dv.z);
            dv.w = fmaf(cc.w, h0[n4].w, dv.w);
        }
        const float dot = (dv.x + dv.y) + (dv.z + dv.w);
        const float x = proj[(size_t)bl * DIP + OFF_X + h * HD + lane];
        const float z = proj[(size_t)bl * DIP + OFF_Z + h * HD + lane];
        const size_t yi = (size_t)bl * DI + h * HD + lane;
        const float yv = yact[yi] + w * dot + Dp * x;
        ybf[yi] = f2bf(yv * z * sigmoidf_(z));
        __syncthreads();
    }
}

extern "C" void kernel_launch(void* const* d_in, const int* in_sizes, int n_in,
                              void* d_out, int out_size, void* d_ws, size_t ws_size,
                              hipStream_t stream) {
    const float* u       = (const float*)d_in[0];
    const float* W_in    = (const float*)d_in[1];
    const float* W_out   = (const float*)d_in[2];
    const float* dt_bias = (const float*)d_in[3];
    const float* D_param = (const float*)d_in[4];
    const float* Bn_g    = (const float*)d_in[5];
    const float* Bn_b    = (const float*)d_in[6];
    const float* Cn_g    = (const float*)d_in[7];
    const float* Cn_b    = (const float*)d_in[8];
    float* out = (float*)d_out;

    float* ws    = (float*)d_ws;
    float* proj  = ws;                          // 4,456,448 f
    float* Bln   = proj + (size_t)BL * DIP;
    float* Cln   = Bln + BL * DS;
    float* Brot  = Cln + BL * DS;
    float* Crot  = Brot + BL * DS;
    float* DTa   = Crot + BL * DS;
    float* deca  = DTa + BL * NH_;
    float* trpa  = deca + BL * NH_;
    float* dtm   = trpa + BL * NH_;
    float* phase = dtm + BL;                    // BL*NA
    float* yact  = phase + BL * NA;             // BL*DI f32
    float* ybf_f = yact + (size_t)BL * DI;      // BL*DI bf16 = 1,048,576 f
    float* shreg = ybf_f + (size_t)BL * DI / 2; // 4,194,304 f shared region

    // aliases
    ushort* ubf   = (ushort*)yact;              // A of in-proj (dead before scanA writes)
    ushort* WinT  = (ushort*)shreg;             // B^T in-proj (dead before scanA's hend)
    float*  hend  = shreg;                      // scanA..scanC
    float*  cpart = shreg;                      // out-proj partials (after scanC)
    ushort* WoutT = (ushort*)proj;              // B^T out-proj (proj dead after scanC)
    ushort* ybf   = (ushort*)ybf_f;

    // 1) bf16 operand prep for in-projection
    cast_bf16<<<dim3((BL * DM / 4 + 255) / 256), dim3(256), 0, stream>>>(u, ubf, BL * DM / 4);
    transpose_cast<<<dim3(DIP / 32, DM / 32), dim3(32, 8), 0, stream>>>(W_in, WinT, DM, DIP);
    // 2) in-projection: bf16 MFMA for cols 0..4224, exact f32 for scalar cols
    gemm_bf16<<<dim3(33, 8, 1), dim3(256), 0, stream>>>(ubf, WinT, proj, DM, DIP, DM, 0);
    skinny_f32<<<dim3(BL), dim3(256), 0, stream>>>(u, W_in, proj);
    // 3) small per-(b,l) ops
    small_ops<<<dim3(BL), dim3(64), 0, stream>>>(proj, dt_bias, Bn_g, Bn_b, Cn_g, Cn_b,
                                                 DTa, deca, trpa, dtm, Bln, Cln);
    // 4) phase cumsum + RoPE
    phase_scan<<<dim3(B_ * NA), dim3(64), 0, stream>>>(proj, dtm, phase);
    rope_apply<<<dim3(BL), dim3(64), 0, stream>>>(phase, Bln, Cln, Brot, Crot);
    // 5) chunked scan
    scanA<<<dim3(B_ * NH_ * NCH), dim3(64), 0, stream>>>(proj, Brot, Crot, DTa, deca, trpa,
                                                         yact, hend);
    scanB<<<dim3(B_ * NH_), dim3(256), 0, stream>>>(deca, hend);
    scanC<<<dim3(B_ * NH_ * NCH), dim3(64), 0, stream>>>(proj, Crot, deca, hend, D_param,
                                                         yact, ybf);
    // 6) out-projection: bf16 MFMA, split-K=4, deterministic reduce
    transpose_cast<<<dim3(DM / 32, DI / 32), dim3(32, 8), 0, stream>>>(W_out, WoutT, DI, DM);
    gemm_bf16<<<dim3(8, 8, 4), dim3(256), 0, stream>>>(ybf, WoutT, cpart, DI, DM, DI / 4,
                                                       (size_t)BL * DM);
    reduce4<<<dim3(1024), dim3(256), 0, stream>>>(cpart, out);
}

// Round 6
// 159.221 us; speedup vs baseline: 6.7957x; 1.2585x over previous
//
#include <hip/hip_runtime.h>
#include <hip/hip_bf16.h>
#include <math.h>

#define B_   2
#define L_   512
#define DM   1024
#define DIP  4352
#define DI   2048
#define NH_  32
#define HD   64
#define DS   64
#define NA   32
#define BL   (B_ * L_)
#define CHK  32
#define NCH  16

// proj slice offsets
#define OFF_Z    0
#define OFF_X    2048
#define OFF_BP   4096
#define OFF_CP   4160
#define OFF_DT   4224
#define OFF_DA   4256
#define OFF_TR   4288
#define OFF_ANG  4320

typedef short bf16x8s __attribute__((ext_vector_type(8)));
typedef float f32x4 __attribute__((ext_vector_type(4)));

__device__ __forceinline__ float softplusf(float x) {
    return x > 0.f ? x + log1pf(expf(-x)) : log1pf(expf(x));
}
__device__ __forceinline__ float sigmoidf_(float x) {
    return 1.f / (1.f + expf(-x));
}
__device__ __forceinline__ float wave_sum(float v) {
#pragma unroll
    for (int off = 32; off; off >>= 1) v += __shfl_xor(v, off);
    return v;
}
__device__ __forceinline__ ushort f2bf(float f) {
    uint u = __float_as_uint(f);
    return (ushort)((u + 0x7fffu + ((u >> 16) & 1u)) >> 16);
}

// ---------------- cast f32 -> bf16 (row-major copy) -------------------------
__global__ __launch_bounds__(256) void cast_bf16(const float* __restrict__ in,
                                                 ushort* __restrict__ outp, int n4) {
    int i = blockIdx.x * 256 + threadIdx.x;
    if (i >= n4) return;
    float4 v = ((const float4*)in)[i];
    uint u0 = (uint)f2bf(v.x) | ((uint)f2bf(v.y) << 16);
    uint u1 = (uint)f2bf(v.z) | ((uint)f2bf(v.w) << 16);
    *(uint2*)&outp[(size_t)i * 4] = make_uint2(u0, u1);
}

// ---------------- transpose + cast: in f32 [R][C] -> out bf16 [C][R] --------
__global__ __launch_bounds__(256) void transpose_cast(const float* __restrict__ in,
                                                      ushort* __restrict__ outp,
                                                      int R, int C) {
    __shared__ ushort t[32][33];
    const int tx = threadIdx.x, ty = threadIdx.y;
    const int c0 = blockIdx.x * 32, r0 = blockIdx.y * 32;
#pragma unroll
    for (int j = 0; j < 4; ++j) {
        int r = r0 + ty + j * 8;
        t[ty + j * 8][tx] = f2bf(in[(size_t)r * C + c0 + tx]);
    }
    __syncthreads();
#pragma unroll
    for (int j = 0; j < 4; ++j) {
        int c = c0 + ty + j * 8;
        outp[(size_t)c * R + r0 + tx] = t[tx][ty + j * 8];
    }
}

// ---------------- bf16 MFMA GEMM: C[M,N](f32) = A[M,K] @ BT[N,K] ------------
__global__ __launch_bounds__(256) void gemm_bf16(const ushort* __restrict__ A,
                                                 const ushort* __restrict__ BT,
                                                 float* __restrict__ C,
                                                 int K, int ldc, int kslice,
                                                 size_t partStride) {
    __shared__ ushort sA[128 * 32];
    __shared__ ushort sB[128 * 32];
    const int tid = threadIdx.x;
    const int l = tid & 63;
    const int w = tid >> 6;
    const int wr = w >> 1, wc = w & 1;
    const int brow = blockIdx.y * 128;
    const int bcol = blockIdx.x * 128;
    const int kstart = blockIdx.z * kslice;
    float* Cp = C + (size_t)blockIdx.z * partStride;

    const int srow = tid >> 2;
    const int gs = tid & 3;
    const int ws0 = gs ^ (srow & 3);
    const int ws1 = gs ^ ((64 + srow) & 3);

    int4 ra0, ra1, rb0, rb1;
    const ushort* Arow0 = A + (size_t)(brow + srow) * K + gs * 8;
    const ushort* Arow1 = A + (size_t)(brow + 64 + srow) * K + gs * 8;
    const ushort* Brow0 = BT + (size_t)(bcol + srow) * K + gs * 8;
    const ushort* Brow1 = BT + (size_t)(bcol + 64 + srow) * K + gs * 8;

    ra0 = *(const int4*)(Arow0 + kstart);
    ra1 = *(const int4*)(Arow1 + kstart);
    rb0 = *(const int4*)(Brow0 + kstart);
    rb1 = *(const int4*)(Brow1 + kstart);

    f32x4 acc[4][4] = {};

    const int kend = kstart + kslice;
    for (int k0 = kstart; k0 < kend; k0 += 32) {
        __syncthreads();
        *(int4*)&sA[(size_t)srow * 32 + ws0 * 8] = ra0;
        *(int4*)&sA[(size_t)(64 + srow) * 32 + ws1 * 8] = ra1;
        *(int4*)&sB[(size_t)srow * 32 + ws0 * 8] = rb0;
        *(int4*)&sB[(size_t)(64 + srow) * 32 + ws1 * 8] = rb1;
        __syncthreads();
        if (k0 + 32 < kend) {
            ra0 = *(const int4*)(Arow0 + k0 + 32);
            ra1 = *(const int4*)(Arow1 + k0 + 32);
            rb0 = *(const int4*)(Brow0 + k0 + 32);
            rb1 = *(const int4*)(Brow1 + k0 + 32);
        }
        bf16x8s af[4], bfr[4];
#pragma unroll
        for (int m = 0; m < 4; ++m) {
            int row = wr * 64 + m * 16 + (l & 15);
            int slot = (l >> 4) ^ (row & 3);
            af[m] = *(const bf16x8s*)&sA[(size_t)row * 32 + slot * 8];
        }
#pragma unroll
        for (int n = 0; n < 4; ++n) {
            int row = wc * 64 + n * 16 + (l & 15);
            int slot = (l >> 4) ^ (row & 3);
            bfr[n] = *(const bf16x8s*)&sB[(size_t)row * 32 + slot * 8];
        }
#pragma unroll
        for (int m = 0; m < 4; ++m)
#pragma unroll
            for (int n = 0; n < 4; ++n)
                acc[m][n] = __builtin_amdgcn_mfma_f32_16x16x32_bf16(af[m], bfr[n], acc[m][n], 0, 0, 0);
    }
#pragma unroll
    for (int m = 0; m < 4; ++m) {
        const int row0 = brow + wr * 64 + m * 16 + (l >> 4) * 4;
#pragma unroll
        for (int n = 0; n < 4; ++n) {
            const int col = bcol + wc * 64 + n * 16 + (l & 15);
#pragma unroll
            for (int r = 0; r < 4; ++r)
                Cp[(size_t)(row0 + r) * ldc + col] = acc[m][n][r];
        }
    }
}

// ---------------- reduce 4 split-K partials --------------------------------
__global__ __launch_bounds__(256) void reduce4(const float* __restrict__ p,
                                               float* __restrict__ outp) {
    const int i = blockIdx.x * 256 + threadIdx.x;
    float4 a = ((const float4*)p)[i];
    float4 b = ((const float4*)(p + 1048576))[i];
    float4 c = ((const float4*)(p + 2097152))[i];
    float4 d = ((const float4*)(p + 3145728))[i];
    float4 s;
    s.x = (a.x + b.x) + (c.x + d.x);
    s.y = (a.y + b.y) + (c.y + d.y);
    s.z = (a.z + b.z) + (c.z + d.z);
    s.w = (a.w + b.w) + (c.w + d.w);
    ((float4*)outp)[i] = s;
}

// ---------------- exact f32 skinny cols (DT/DA/TR/ANG), 4 rows/block --------
__global__ __launch_bounds__(256) void skinny_f32(const float* __restrict__ u,
                                                  const float* __restrict__ W_in,
                                                  float* __restrict__ proj) {
    __shared__ float u4[4][1024];
    __shared__ float part[4][256];
    const int tid = threadIdx.x;
    const int blr = blockIdx.x * 4;
#pragma unroll
    for (int q = 0; q < 4; ++q) {
        int idx = q * 256 + tid;            // 0..1023 float4 slots
        int r = idx >> 8, s = idx & 255;
        *(float4*)&u4[r][s * 4] = *(const float4*)&u[(size_t)(blr + r) * DM + s * 4];
    }
    __syncthreads();
    const int col = tid & 127;
    const int half = tid >> 7;
    float s0 = 0.f, s1 = 0.f, s2 = 0.f, s3 = 0.f;
    const float* wp = W_in + (size_t)(half * 512) * DIP + OFF_DT + col;
#pragma unroll 8
    for (int k = 0; k < 512; ++k) {
        float wv = wp[(size_t)k * DIP];
        s0 = fmaf(u4[0][half * 512 + k], wv, s0);
        s1 = fmaf(u4[1][half * 512 + k], wv, s1);
        s2 = fmaf(u4[2][half * 512 + k], wv, s2);
        s3 = fmaf(u4[3][half * 512 + k], wv, s3);
    }
    part[0][tid] = s0; part[1][tid] = s1; part[2][tid] = s2; part[3][tid] = s3;
    __syncthreads();
    if (tid < 128) {
#pragma unroll
        for (int r = 0; r < 4; ++r)
            proj[(size_t)(blr + r) * DIP + OFF_DT + tid] = part[r][tid] + part[r][128 + tid];
    }
}

// ---------- per-(b,l) small ops ---------------------------------------------
__global__ __launch_bounds__(64) void small_ops(const float* __restrict__ proj,
                                                const float* __restrict__ dt_bias,
                                                const float* __restrict__ Bn_g,
                                                const float* __restrict__ Bn_b,
                                                const float* __restrict__ Cn_g,
                                                const float* __restrict__ Cn_b,
                                                float* __restrict__ DTa,
                                                float* __restrict__ deca,
                                                float* __restrict__ trpa,
                                                float* __restrict__ dtm,
                                                float* __restrict__ Bln,
                                                float* __restrict__ Cln) {
    const int bl = blockIdx.x;
    const int lane = threadIdx.x;
    const float* p = proj + (size_t)bl * DIP;

    float dt = 0.f;
    if (lane < NH_) {
        dt = softplusf(p[OFF_DT + lane] + dt_bias[lane]);
        DTa[bl * NH_ + lane] = dt;
        float a = -softplusf(p[OFF_DA + lane]);
        a = fminf(a, -1e-4f);
        deca[bl * NH_ + lane] = expf(a * dt);
        trpa[bl * NH_ + lane] = sigmoidf_(p[OFF_TR + lane]);
    }
    float s = wave_sum(dt);
    if (lane == 0) dtm[bl] = s * (1.f / NH_);

    {
        float v = p[OFF_BP + lane];
        float m = wave_sum(v) * (1.f / 64.f);
        float d = v - m;
        float var = wave_sum(d * d) * (1.f / 64.f);
        Bln[bl * DS + lane] = d / sqrtf(var + 1e-5f) * Bn_g[lane] + Bn_b[lane];
    }
    {
        float v = p[OFF_CP + lane];
        float m = wave_sum(v) * (1.f / 64.f);
        float d = v - m;
        float var = wave_sum(d * d) * (1.f / 64.f);
        Cln[bl * DS + lane] = d / sqrtf(var + 1e-5f) * Cn_g[lane] + Cn_b[lane];
    }
}

// ---------- blocked parallel cumsum of phase --------------------------------
__global__ __launch_bounds__(64) void phase_scan(const float* __restrict__ proj,
                                                 const float* __restrict__ dtm,
                                                 float* __restrict__ phase) {
    const int b = blockIdx.x >> 5;
    const int a = blockIdx.x & 31;
    const int lane = threadIdx.x;
    float s[8];
    float run = 0.f;
#pragma unroll
    for (int j = 0; j < 8; ++j) {
        const int bl = b * L_ + lane * 8 + j;
        run += proj[(size_t)bl * DIP + OFF_ANG + a] * dtm[bl];
        s[j] = run;
    }
    float inc = run;
#pragma unroll
    for (int off = 1; off < 64; off <<= 1) {
        float v = __shfl_up(inc, off);
        if (lane >= off) inc += v;
    }
    const float excl = inc - run;
#pragma unroll
    for (int j = 0; j < 8; ++j)
        phase[(b * L_ + lane * 8 + j) * NA + a] = excl + s[j];
}

// ---------- parallel RoPE application ---------------------------------------
__global__ __launch_bounds__(64) void rope_apply(const float* __restrict__ phase,
                                                 const float* __restrict__ Bln,
                                                 const float* __restrict__ Cln,
                                                 float* __restrict__ Brot,
                                                 float* __restrict__ Crot) {
    const int bl = blockIdx.x;
    const int lane = threadIdx.x;
    const int pr = lane >> 1;
    const float ph = phase[bl * NA + pr];
    float sn, cs;
    __sincosf(ph, &sn, &cs);
    const bool odd = lane & 1;
    {
        float ve = Bln[bl * DS + pr * 2], vo = Bln[bl * DS + pr * 2 + 1];
        Brot[bl * DS + lane] = odd ? (ve * sn + vo * cs) : (ve * cs - vo * sn);
    }
    {
        float ve = Cln[bl * DS + pr * 2], vo = Cln[bl * DS + pr * 2 + 1];
        Crot[bl * DS + lane] = odd ? (ve * sn + vo * cs) : (ve * cs - vo * sn);
    }
}

// ---------- scan phase A: chunk-staged, barrier-free inner loop -------------
__global__ __launch_bounds__(64) void scanA(const float* __restrict__ proj,
                                            const float* __restrict__ Brot,
                                            const float* __restrict__ Crot,
                                            const float* __restrict__ DTa,
                                            const float* __restrict__ deca,
                                            const float* __restrict__ trpa,
                                            float* __restrict__ yact,
                                            float* __restrict__ hend) {
    __shared__ float Ball[CHK + 1][64];
    __shared__ float Call[CHK][64];
    __shared__ float sdl[CHK], sdt[CHK], ste[CHK];
    const int blk = blockIdx.x;
    const int c  = blk & 15;
    const int bh = blk >> 4;
    const int h  = bh & 31;
    const int b  = bh >> 5;
    const int lane = threadIdx.x;   // = p
    const int bl0 = b * L_ + c * CHK;

    // stage chunk B (rows -1..CHK-1), C, and per-step scalars
    Ball[0][lane] = (c > 0) ? Brot[(bl0 - 1) * DS + lane] : 0.f;
#pragma unroll 4
    for (int r = 0; r < CHK; ++r) {
        Ball[r + 1][lane] = Brot[(bl0 + r) * DS + lane];
        Call[r][lane]     = Crot[(bl0 + r) * DS + lane];
    }
    if (lane < CHK) {
        sdl[lane] = deca[(bl0 + lane) * NH_ + h];
        sdt[lane] = DTa[(bl0 + lane) * NH_ + h];
        ste[lane] = trpa[(bl0 + lane) * NH_ + h];
    }
    __syncthreads();

    // per-lane per-step coefficients (registers, const-indexed)
    float dl[CHK], ac[CHK], bc[CHK];
    float xprev = (c > 0) ? proj[(size_t)(bl0 - 1) * DIP + OFF_X + h * HD + lane] : 0.f;
#pragma unroll
    for (int i = 0; i < CHK; ++i) {
        float xi = proj[(size_t)(bl0 + i) * DIP + OFF_X + h * HD + lane];
        float d = sdl[i], dt = sdt[i], te = ste[i];
        dl[i] = d;
        ac[i] = dt * te * xi;
        bc[i] = dt * (1.f - te) * xprev;
        xprev = xi;
    }

    float y[CHK];
#pragma unroll
    for (int i = 0; i < CHK; ++i) y[i] = 0.f;

    const size_t hbase = (size_t)(bh * NCH + c) * 64 * 64;
    for (int n4 = 0; n4 < 16; ++n4) {           // runtime loop over state quads
        float4 h4 = make_float4(0.f, 0.f, 0.f, 0.f);
        float4 bp = *(const float4*)&Ball[0][n4 * 4];
#pragma unroll
        for (int i = 0; i < CHK; ++i) {
            float4 bb = *(const float4*)&Ball[i + 1][n4 * 4];
            float4 cc = *(const float4*)&Call[i][n4 * 4];
            h4.x = fmaf(dl[i], h4.x, fmaf(ac[i], bb.x, bc[i] * bp.x));
            h4.y = fmaf(dl[i], h4.y, fmaf(ac[i], bb.y, bc[i] * bp.y));
            h4.z = fmaf(dl[i], h4.z, fmaf(ac[i], bb.z, bc[i] * bp.z));
            h4.w = fmaf(dl[i], h4.w, fmaf(ac[i], bb.w, bc[i] * bp.w));
            y[i] = fmaf(h4.x, cc.x, y[i]);
            y[i] = fmaf(h4.y, cc.y, y[i]);
            y[i] = fmaf(h4.z, cc.z, y[i]);
            y[i] = fmaf(h4.w, cc.w, y[i]);
            bp = bb;
        }
        const size_t hb = hbase + (size_t)(n4 * 4) * 64 + lane;
        hend[hb]       = h4.x;
        hend[hb + 64]  = h4.y;
        hend[hb + 128] = h4.z;
        hend[hb + 192] = h4.w;
    }
#pragma unroll
    for (int i = 0; i < CHK; ++i)
        yact[(size_t)(bl0 + i) * DI + h * HD + lane] = y[i];
}

// ---------- scan phase B: combine chunk states (4 slices/bh, prefetch) ------
__global__ __launch_bounds__(256) void scanB(const float* __restrict__ deca,
                                             float* __restrict__ hend) {
    __shared__ float Pl[NCH];
    const int bh = blockIdx.x >> 2;
    const int slice = blockIdx.x & 3;
    const int h = bh & 31, b = bh >> 5;
    const int tid = threadIdx.x;
    if (tid < NCH) {
        float p = 1.f;
        for (int j = 0; j < CHK; ++j)
            p *= deca[(b * L_ + tid * CHK + j) * NH_ + h];
        Pl[tid] = p;
    }
    __syncthreads();
    const size_t eoff = (size_t)slice * 1024 + tid * 4;
    const size_t cbase = (size_t)bh * NCH * 4096;
    float4 run = make_float4(0.f, 0.f, 0.f, 0.f);
    float4 cur = *(const float4*)&hend[cbase + eoff];
    float4 nx  = *(const float4*)&hend[cbase + 4096 + eoff];
    for (int cc = 0; cc < NCH - 1; ++cc) {
        float4 fut = make_float4(0.f, 0.f, 0.f, 0.f);
        if (cc + 2 <= NCH - 2)
            fut = *(const float4*)&hend[cbase + (size_t)(cc + 2) * 4096 + eoff];
        const float Pc = Pl[cc];
        run.x = fmaf(Pc, run.x, cur.x);
        run.y = fmaf(Pc, run.y, cur.y);
        run.z = fmaf(Pc, run.z, cur.z);
        run.w = fmaf(Pc, run.w, cur.w);
        *(float4*)&hend[cbase + (size_t)cc * 4096 + eoff] = run;
        cur = nx; nx = fut;
    }
}

// ---------- scan phase C: h0 in regs, unrolled dot, gate -> bf16 ------------
__global__ __launch_bounds__(64) void scanC(const float* __restrict__ proj,
                                            const float* __restrict__ Crot,
                                            const float* __restrict__ deca,
                                            const float* __restrict__ hend,
                                            const float* __restrict__ D_param,
                                            const float* __restrict__ yact,
                                            ushort* __restrict__ ybf) {
    __shared__ float Call[CHK][64];
    __shared__ float sdl[CHK];
    const int blk = blockIdx.x;
    const int c = blk & 15;
    const int bh = blk >> 4;
    const int h = bh & 31, b = bh >> 5;
    const int lane = threadIdx.x;
    const int bl0 = b * L_ + c * CHK;

#pragma unroll 4
    for (int r = 0; r < CHK; ++r)
        Call[r][lane] = Crot[(bl0 + r) * DS + lane];
    if (lane < CHK) sdl[lane] = deca[(bl0 + lane) * NH_ + h];

    float4 h0[16];
    if (c > 0) {
        const size_t base = (size_t)(bh * NCH + (c - 1)) * 4096;
#pragma unroll
        for (int n4 = 0; n4 < 16; ++n4) {
            h0[n4].x = hend[base + (size_t)(n4 * 4 + 0) * 64 + lane];
            h0[n4].y = hend[base + (size_t)(n4 * 4 + 1) * 64 + lane];
            h0[n4].z = hend[base + (size_t)(n4 * 4 + 2) * 64 + lane];
            h0[n4].w = hend[base + (size_t)(n4 * 4 + 3) * 64 + lane];
        }
    } else {
#pragma unroll
        for (int n4 = 0; n4 < 16; ++n4) h0[n4] = make_float4(0.f, 0.f, 0.f, 0.f);
    }
    __syncthreads();

    const float Dp = D_param[h];
    float w = 1.f;
    // software-pipelined per-step loads
    float xn = proj[(size_t)bl0 * DIP + OFF_X + h * HD + lane];
    float zn = proj[(size_t)bl0 * DIP + OFF_Z + h * HD + lane];
    float yn = yact[(size_t)bl0 * DI + h * HD + lane];
    for (int i = 0; i < CHK; ++i) {
        const float x = xn, z = zn, ya = yn;
        if (i + 1 < CHK) {
            xn = proj[(size_t)(bl0 + i + 1) * DIP + OFF_X + h * HD + lane];
            zn = proj[(size_t)(bl0 + i + 1) * DIP + OFF_Z + h * HD + lane];
            yn = yact[(size_t)(bl0 + i + 1) * DI + h * HD + lane];
        }
        w *= sdl[i];
        float corr = 0.f;
        const float4* Cc = (const float4*)Call[i];
#pragma unroll
        for (int n4 = 0; n4 < 16; ++n4) {
            float4 cc = Cc[n4];
            corr = fmaf(h0[n4].x, cc.x, corr);
            corr = fmaf(h0[n4].y, cc.y, corr);
            corr = fmaf(h0[n4].z, cc.z, corr);
            corr = fmaf(h0[n4].w, cc.w, corr);
        }
        const float yv = ya + w * corr + Dp * x;
        ybf[(size_t)(bl0 + i) * DI + h * HD + lane] = f2bf(yv * z * sigmoidf_(z));
    }
}

extern "C" void kernel_launch(void* const* d_in, const int* in_sizes, int n_in,
                              void* d_out, int out_size, void* d_ws, size_t ws_size,
                              hipStream_t stream) {
    const float* u       = (const float*)d_in[0];
    const float* W_in    = (const float*)d_in[1];
    const float* W_out   = (const float*)d_in[2];
    const float* dt_bias = (const float*)d_in[3];
    const float* D_param = (const float*)d_in[4];
    const float* Bn_g    = (const float*)d_in[5];
    const float* Bn_b    = (const float*)d_in[6];
    const float* Cn_g    = (const float*)d_in[7];
    const float* Cn_b    = (const float*)d_in[8];
    float* out = (float*)d_out;

    float* ws    = (float*)d_ws;
    float* proj  = ws;                          // 4,456,448 f
    float* Bln   = proj + (size_t)BL * DIP;
    float* Cln   = Bln + BL * DS;
    float* Brot  = Cln + BL * DS;
    float* Crot  = Brot + BL * DS;
    float* DTa   = Crot + BL * DS;
    float* deca  = DTa + BL * NH_;
    float* trpa  = deca + BL * NH_;
    float* dtm   = trpa + BL * NH_;
    float* phase = dtm + BL;                    // BL*NA
    float* yact  = phase + BL * NA;             // BL*DI f32
    float* ybf_f = yact + (size_t)BL * DI;      // BL*DI bf16
    float* shreg = ybf_f + (size_t)BL * DI / 2; // 4,194,304 f shared region

    // aliases
    ushort* ubf   = (ushort*)yact;              // A of in-proj (dead before scanA writes)
    ushort* WinT  = (ushort*)shreg;             // B^T in-proj (dead before scanA's hend)
    float*  hend  = shreg;                      // scanA..scanC
    float*  cpart = shreg;                      // out-proj partials (after scanC)
    ushort* WoutT = (ushort*)proj;              // B^T out-proj (proj dead after scanC)
    ushort* ybf   = (ushort*)ybf_f;

    // 1) bf16 operand prep for in-projection
    cast_bf16<<<dim3((BL * DM / 4 + 255) / 256), dim3(256), 0, stream>>>(u, ubf, BL * DM / 4);
    transpose_cast<<<dim3(DIP / 32, DM / 32), dim3(32, 8), 0, stream>>>(W_in, WinT, DM, DIP);
    // 2) in-projection: bf16 MFMA for cols 0..4224, exact f32 for scalar cols
    gemm_bf16<<<dim3(33, 8, 1), dim3(256), 0, stream>>>(ubf, WinT, proj, DM, DIP, DM, 0);
    skinny_f32<<<dim3(BL / 4), dim3(256), 0, stream>>>(u, W_in, proj);
    // 3) small per-(b,l) ops
    small_ops<<<dim3(BL), dim3(64), 0, stream>>>(proj, dt_bias, Bn_g, Bn_b, Cn_g, Cn_b,
                                                 DTa, deca, trpa, dtm, Bln, Cln);
    // 4) phase cumsum + RoPE
    phase_scan<<<dim3(B_ * NA), dim3(64), 0, stream>>>(proj, dtm, phase);
    rope_apply<<<dim3(BL), dim3(64), 0, stream>>>(phase, Bln, Cln, Brot, Crot);
    // 5) chunked scan
    scanA<<<dim3(B_ * NH_ * NCH), dim3(64), 0, stream>>>(proj, Brot, Crot, DTa, deca, trpa,
                                                         yact, hend);
    scanB<<<dim3(B_ * NH_ * 4), dim3(256), 0, stream>>>(deca, hend);
    scanC<<<dim3(B_ * NH_ * NCH), dim3(64), 0, stream>>>(proj, Crot, deca, hend, D_param,
                                                         yact, ybf);
    // 6) out-projection: bf16 MFMA, split-K=4, deterministic reduce
    transpose_cast<<<dim3(DM / 32, DI / 32), dim3(32, 8), 0, stream>>>(W_out, WoutT, DI, DM);
    gemm_bf16<<<dim3(8, 8, 4), dim3(256), 0, stream>>>(ybf, WoutT, cpart, DI, DM, DI / 4,
                                                       (size_t)BL * DM);
    reduce4<<<dim3(1024), dim3(256), 0, stream>>>(cpart, out);
}